// Round 5
// baseline (2116.616 us; speedup 1.0000x reference)
//
#include <hip/hip_runtime.h>
#include <math.h>

#define NN 100000
#define EIE 1600000
#define ECE 800000
#define GG 2000
#define FDIM 512
#define CC 128
#define BNEPS 1e-5f

static inline int cdiv(long a, long b){ return (int)((a+b-1)/b); }

typedef __attribute__((ext_vector_type(8))) short short8;
typedef __attribute__((ext_vector_type(4))) float f32x4;

__device__ __forceinline__ unsigned short f2bf(float f){
  unsigned u = __float_as_uint(f);
  u += 0x7fffu + ((u >> 16) & 1u);
  return (unsigned short)(u >> 16);
}
__device__ __forceinline__ float bf2f(unsigned short h){
  return __uint_as_float(((unsigned)h) << 16);
}

// ---------------- degree counts ----------------
__global__ void k_count(const int* __restrict__ isrc, const int* __restrict__ idst,
                        const int* __restrict__ cdst,
                        int* __restrict__ deg_i, int* __restrict__ deg_c, int* __restrict__ dout) {
  int e = blockIdx.x*256 + threadIdx.x;
  if (e < EIE) { atomicAdd(&deg_i[idst[e]], 1); atomicAdd(&dout[isrc[e]], 1); }
  if (e < ECE) { atomicAdd(&deg_c[cdst[e]], 1); }
}

// ---------------- exclusive scan of the two degree arrays ----------------
__global__ void k_scan2(const int* __restrict__ deg_i, int* __restrict__ offs_i,
                        const int* __restrict__ deg_c, int* __restrict__ offs_c) {
  const int* deg = blockIdx.x ? deg_c : deg_i;
  int* offs      = blockIdx.x ? offs_c : offs_i;
  __shared__ int sums[256];
  int t = threadIdx.x;
  const int chunk = (NN + 255) / 256;
  int lo = t*chunk, hi = min(lo + chunk, NN);
  int s = 0;
  for (int i = lo; i < hi; ++i) s += deg[i];
  sums[t] = s;
  __syncthreads();
  if (t == 0) { int run = 0; for (int i = 0; i < 256; ++i) { int v = sums[i]; sums[i] = run; run += v; } }
  __syncthreads();
  int run = sums[t];
  for (int i = lo; i < hi; ++i) { offs[i] = run; run += deg[i]; }
  if (t == 255) offs[NN] = run;
}

// ---------------- CSR fill ----------------
__global__ void k_fill(const int* __restrict__ src, const int* __restrict__ dst,
                       const int* __restrict__ offs, int* __restrict__ cnt,
                       int* __restrict__ eid, int E) {
  int e = blockIdx.x*256 + threadIdx.x;
  if (e >= E) return;
  int d = dst[e];
  int p = offs[d] + atomicAdd(&cnt[d], 1);
  eid[p] = src[e];
}

// ---------------- pack all W into bf16 hi/lo, k-tile fragment order ----------------
// layout per 256x FIN matrix: ktile t=k>>5, then ((n>>4)*4 + ((k>>3)&3))*128 + (n&15)*8 + (k&7)
__device__ __forceinline__ size_t wt_off(int n, int k) {
  return (size_t)(k >> 5)*8192 + (((n >> 4)*4 + ((k >> 3) & 3))*16 + (n & 15))*8 + (k & 7);
}
__global__ void k_pack_all(const float* __restrict__ Wgc1, const float* __restrict__ Wgat1,
                           const float* __restrict__ Wgc2, const float* __restrict__ Wgat2,
                           const float* __restrict__ Wgc3, const float* __restrict__ Wgat3,
                           unsigned short* __restrict__ Wth1, unsigned short* __restrict__ Wtl1,
                           unsigned short* __restrict__ Wth2, unsigned short* __restrict__ Wtl2,
                           unsigned short* __restrict__ Wth3, unsigned short* __restrict__ Wtl3) {
  int t = blockIdx.x*256 + threadIdx.x;
  const float *W1, *W2; unsigned short *oh, *ol; int FIN, tt;
  if (t < 131072)      { W1=Wgc1; W2=Wgat1; oh=Wth1; ol=Wtl1; FIN=512; tt=t; }
  else if (t < 163840) { W1=Wgc2; W2=Wgat2; oh=Wth2; ol=Wtl2; FIN=128; tt=t-131072; }
  else if (t < 196608) { W1=Wgc3; W2=Wgat3; oh=Wth3; ol=Wtl3; FIN=128; tt=t-163840; }
  else return;
  int n = tt / FIN, k = tt % FIN;
  float v = (n < 128) ? W1[(size_t)k*128 + n] : W2[(size_t)k*128 + (n-128)];
  unsigned short h = f2bf(v);
  size_t o = wt_off(n, k);
  oh[o] = h;
  ol[o] = f2bf(v - bf2f(h));
}

// ---------------- dual MFMA GEMM (bf16x3): Y1=(x@W1)*dout^-1/2, Y2=x@W2 ----------------
// 128 rows x 256 cols per 512-thread block (8 waves, 2x4, 64x64 wave tiles).
// LDS in MFMA-fragment order -> all ds accesses lane-contiguous. Optional BN affine on x.
template<int FIN, bool BN>
__global__ __launch_bounds__(512)
void k_gemm2(const float* __restrict__ x, const unsigned short* __restrict__ Bh,
             const unsigned short* __restrict__ Bl, const int* __restrict__ rowdeg,
             const float* __restrict__ bnsc, const float* __restrict__ bnsh,
             float* __restrict__ Y1, float* __restrict__ Y2) {
  __shared__ __attribute__((aligned(16))) unsigned short sAh[4096];   // 8 KB
  __shared__ __attribute__((aligned(16))) unsigned short sAl[4096];
  __shared__ __attribute__((aligned(16))) unsigned short sBh[8192];   // 16 KB
  __shared__ __attribute__((aligned(16))) unsigned short sBl[8192];
  int tid = threadIdx.x;
  int row0 = blockIdx.x*128;
  int lane = tid & 63, wid = tid >> 6;
  int wm = wid >> 2, wn = wid & 3;          // 2 x 4 wave grid
  int l15 = lane & 15, quad = lane >> 4;

  f32x4 acc[4][4];
  #pragma unroll
  for (int mt = 0; mt < 4; ++mt)
    #pragma unroll
    for (int nt = 0; nt < 4; ++nt) acc[mt][nt] = (f32x4){0.f,0.f,0.f,0.f};

  for (int k0 = 0; k0 < FIN; k0 += 32) {
    // stage A: 128 rows x 32 k fp32 -> (BN affine) -> bf16 h/l, fragment order
    #pragma unroll
    for (int i = 0; i < 2; ++i) {
      int idx = tid + i*512;
      int r = idx >> 3, c = idx & 7;       // c = float4 chunk (k = c*4)
      int gr = row0 + r; if (gr > NN-1) gr = NN-1;
      float4 v = *(const float4*)(x + (size_t)gr*FIN + k0 + c*4);
      if (BN) {
        float4 s4 = *(const float4*)(bnsc + k0 + c*4);
        float4 h4 = *(const float4*)(bnsh + k0 + c*4);
        v.x = v.x*s4.x + h4.x; v.y = v.y*s4.y + h4.y;
        v.z = v.z*s4.z + h4.z; v.w = v.w*s4.w + h4.w;
      }
      ushort4 hh, ll;
      hh.x = f2bf(v.x); hh.y = f2bf(v.y); hh.z = f2bf(v.z); hh.w = f2bf(v.w);
      ll.x = f2bf(v.x - bf2f(hh.x)); ll.y = f2bf(v.y - bf2f(hh.y));
      ll.z = f2bf(v.z - bf2f(hh.z)); ll.w = f2bf(v.w - bf2f(hh.w));
      int off = (((r>>4)*4 + (c>>1))*16 + (r&15))*8 + (c&1)*4;
      *(ushort4*)&sAh[off] = hh;
      *(ushort4*)&sAl[off] = ll;
    }
    // stage B: pure linear copy of this k-tile's fragment block (coalesced)
    const unsigned short* bhk = Bh + (size_t)k0*256;
    const unsigned short* blk = Bl + (size_t)k0*256;
    #pragma unroll
    for (int i = 0; i < 2; ++i) {
      int idx = tid + i*512;
      *(float4*)&sBh[idx*8] = *(const float4*)(bhk + idx*8);
      *(float4*)&sBl[idx*8] = *(const float4*)(blk + idx*8);
    }
    __syncthreads();
    short8 ah[4], al_[4];
    #pragma unroll
    for (int mt = 0; mt < 4; ++mt) {
      int off = (((wm*4+mt)*4 + quad)*16 + l15)*8;
      ah[mt]  = *(const short8*)&sAh[off];
      al_[mt] = *(const short8*)&sAl[off];
    }
    #pragma unroll
    for (int nt = 0; nt < 4; ++nt) {
      int off = (((wn*4+nt)*4 + quad)*16 + l15)*8;
      short8 bh = *(const short8*)&sBh[off];
      short8 bl = *(const short8*)&sBl[off];
      #pragma unroll
      for (int mt = 0; mt < 4; ++mt) {
        acc[mt][nt] = __builtin_amdgcn_mfma_f32_16x16x32_bf16(ah[mt],  bh, acc[mt][nt], 0,0,0);
        acc[mt][nt] = __builtin_amdgcn_mfma_f32_16x16x32_bf16(ah[mt],  bl, acc[mt][nt], 0,0,0);
        acc[mt][nt] = __builtin_amdgcn_mfma_f32_16x16x32_bf16(al_[mt], bh, acc[mt][nt], 0,0,0);
      }
    }
    __syncthreads();
  }
  // epilogue: D layout col=lane&15, row=quad*4+reg. wn<2 -> Y1, else Y2.
  float* Y = (wn < 2) ? Y1 : Y2;
  int colbase = (wn & 1)*64;
  #pragma unroll
  for (int mt = 0; mt < 4; ++mt) {
    #pragma unroll
    for (int r = 0; r < 4; ++r) {
      int row = row0 + (wm*4+mt)*16 + quad*4 + r;
      if (row >= NN) continue;
      float sc = (wn < 2) ? rsqrtf((float)max(rowdeg[row], 1)) : 1.0f;
      #pragma unroll
      for (int nt = 0; nt < 4; ++nt)
        Y[(size_t)row*CC + colbase + nt*16 + l15] = acc[mt][nt][r]*sc;
    }
  }
}

// ---------------- el/er: wave per node, coalesced float2 + shuffle reduce ----------------
template<int H>
__global__ __launch_bounds__(256)
void k_elr2(const float* __restrict__ f, const float* __restrict__ al,
            const float* __restrict__ ar, float* __restrict__ el, float* __restrict__ er) {
  int lane = threadIdx.x & 63;
  int n = blockIdx.x*4 + (threadIdx.x >> 6);
  if (n >= NN) return;
  int c2 = lane*2;
  float2 v = *(const float2*)(f + (size_t)n*CC + c2);
  float2 a = *(const float2*)(al + c2);       // [H][D] flat == [CC]
  float2 b = *(const float2*)(ar + c2);
  float pa = v.x*a.x + v.y*a.y;
  float pb = v.x*b.x + v.y*b.y;
  const int W = (H == 1) ? 64 : 16;           // lanes per head group
  #pragma unroll
  for (int m = W>>1; m >= 1; m >>= 1) { pa += __shfl_xor(pa, m); pb += __shfl_xor(pb, m); }
  if ((lane & (W-1)) == 0) {
    int h = lane / W;
    el[(size_t)n*H + h] = pa;
    er[(size_t)n*H + h] = pb;
  }
}

// ---------------- fused gather: GraphConv + GAT + biases + leaky, wave per row ----------
// NOTE: segment-max shift omitted — alpha = ex/sum is shift-invariant; |e| is O(1) here.
template<int H, bool ATT, bool LEAKY>
__global__ __launch_bounds__(256)
void k_gather_fused(const float* __restrict__ A1, const float* __restrict__ A2,
                    const int* __restrict__ offs_i, const int* __restrict__ eid_i,
                    const int* __restrict__ offs_c, const int* __restrict__ eid_c,
                    const float* __restrict__ el, const float* __restrict__ er,
                    const float* __restrict__ bgc, const float* __restrict__ bgat,
                    float* __restrict__ out, float* __restrict__ att) {
  int lane = threadIdx.x & 63;
  int row = blockIdx.x*4 + (threadIdx.x >> 6);
  if (row >= NN) return;
  int c2 = lane*2;
  // GraphConv aggregation over inter in-edges
  int lo = offs_i[row], hi = offs_i[row+1];
  float ax = 0.f, ay = 0.f;
  for (int j = lo; j < hi; ++j) {
    int s = eid_i[j];
    float2 v = *(const float2*)(A1 + (size_t)s*CC + c2);
    ax += v.x; ay += v.y;
  }
  float sc = rsqrtf((float)max(hi - lo, 1));
  // GAT over cross in-edges
  int h = (c2*H) >> 7;
  float erd = er[(size_t)row*H + h];
  int lo2 = offs_c[row], hi2 = offs_c[row+1];
  float denom = 0.f;
  for (int j = lo2; j < hi2; ++j) {
    int s = eid_c[j];
    float v = el[s*H+h] + erd;
    v = (v >= 0.f) ? v : 0.2f*v;
    denom += __expf(v);
  }
  float inv = (denom > 0.f) ? 1.0f/denom : 0.f;
  float gx = 0.f, gy = 0.f;
  for (int j = lo2; j < hi2; ++j) {
    int s = eid_c[j];
    float v = el[s*H+h] + erd;
    v = (v >= 0.f) ? v : 0.2f*v;
    float alpha = __expf(v) * inv;
    float2 x = *(const float2*)(A2 + (size_t)s*CC + c2);
    gx += alpha*x.x; gy += alpha*x.y;
    if (ATT) { if (lane == 0) atomicAdd(&att[s], alpha); }  // H==1 only
  }
  float2 b1 = *(const float2*)(bgc + c2);
  float2 b2 = *(const float2*)(bgat + c2);
  float ox = ax*sc + b1.x + gx + b2.x;
  float oy = ay*sc + b1.y + gy + b2.y;
  if (LEAKY) {
    ox = (ox >= 0.f) ? ox : 0.2f*ox;
    oy = (oy >= 0.f) ? oy : 0.2f*oy;
  }
  *(float2*)(out + (size_t)row*CC + c2) = make_float2(ox, oy);
}

// ---------------- batchnorm stats ----------------
__global__ void k_bn_stats(const float* __restrict__ t, float* __restrict__ cs, float* __restrict__ cq) {
  __shared__ float ls[256], lq[256];
  int col = threadIdx.x & 127, half = threadIdx.x >> 7;
  float s = 0.f, q = 0.f;
  for (int r = blockIdx.x*2 + half; r < NN; r += gridDim.x*2) {
    float v = t[(size_t)r*CC + col]; s += v; q += v*v;
  }
  ls[threadIdx.x] = s; lq[threadIdx.x] = q;
  __syncthreads();
  if (half == 0) {
    atomicAdd(&cs[col], ls[threadIdx.x] + ls[threadIdx.x+128]);
    atomicAdd(&cq[col], lq[threadIdx.x] + lq[threadIdx.x+128]);
  }
}

// ---------------- BN affine coefficients: h = t*sc + sh ----------------
__global__ void k_bn_coef(const float* __restrict__ cs, const float* __restrict__ cq,
                          const float* __restrict__ g, const float* __restrict__ be,
                          float* __restrict__ sc, float* __restrict__ sh) {
  int c = threadIdx.x;
  float mu = cs[c] * (1.f/NN);
  float var = cq[c] * (1.f/NN) - mu*mu;
  float r = rsqrtf(var + BNEPS);
  float s = g[c]*r;
  sc[c] = s;
  sh[c] = be[c] - s*mu;
}

// ---------------- pooling (sorted graph_ids) with fused BN apply ----------------
__global__ void k_pool_bn(const float* __restrict__ t, const float* __restrict__ att,
                          const int* __restrict__ gids, const float* __restrict__ bnsc,
                          const float* __restrict__ bnsh, float* __restrict__ frag) {
  int g = blockIdx.x;
  __shared__ int se[2];
  if (threadIdx.x < 2) {
    int target = g + threadIdx.x;
    int lo = 0, hi = NN;
    while (lo < hi) { int mid = (lo + hi) >> 1; if (gids[mid] < target) lo = mid + 1; else hi = mid; }
    se[threadIdx.x] = lo;
  }
  __syncthreads();
  int lo = se[0], hi = se[1];
  int col = threadIdx.x;
  float scv = bnsc[col], shv = bnsh[col];
  float acc = 0.f;
  for (int n = lo; n < hi; ++n) acc += (t[(size_t)n*CC + col]*scv + shv) * att[n];
  frag[(size_t)g*CC + col] = acc / (float)max(hi - lo, 1);
}

// ---------------- one full layer ----------------
template<int FIN, int H, bool BN, bool ATT, bool LEAKY>
static void run_layer(const float* x, const float* bgc,
                      const float* al, const float* ar, const float* bgat,
                      const float* g, const float* be,
                      const int* offs_i, const int* eid_i, const int* offs_c, const int* eid_c,
                      const int* dout, const unsigned short* Wth, const unsigned short* Wtl,
                      float* A1, float* A2, float* B, float* el, float* er,
                      float* cs, float* cq, float* bnsc, float* bnsh,
                      float* att, hipStream_t stream) {
  k_gemm2<FIN,BN><<<cdiv(NN,128), 512, 0, stream>>>(x, Wth, Wtl, dout, bnsc, bnsh, A1, A2);
  k_elr2<H><<<cdiv(NN,4), 256, 0, stream>>>(A2, al, ar, el, er);
  k_gather_fused<H,ATT,LEAKY><<<cdiv(NN,4), 256, 0, stream>>>(A1, A2, offs_i, eid_i,
                                                              offs_c, eid_c, el, er,
                                                              bgc, bgat, B, att);
  hipMemsetAsync(cs, 0, 2*CC*sizeof(float), stream);   // cs,cq contiguous
  k_bn_stats<<<512, 256, 0, stream>>>(B, cs, cq);
  k_bn_coef<<<1, 128, 0, stream>>>(cs, cq, g, be, bnsc, bnsh);
}

extern "C" void kernel_launch(void* const* d_in, const int* in_sizes, int n_in,
                              void* d_out, int out_size, void* d_ws, size_t ws_size,
                              hipStream_t stream) {
  const float* feat  = (const float*)d_in[0];
  const int* isrc    = (const int*)d_in[1];
  const int* idst    = (const int*)d_in[2];
  const int* csrc    = (const int*)d_in[3];
  const int* cdst    = (const int*)d_in[4];
  const int* gids    = (const int*)d_in[5];
  const float* W_gc1 = (const float*)d_in[6];  const float* b_gc1 = (const float*)d_in[7];
  const float* W_gat1= (const float*)d_in[8];  const float* al1   = (const float*)d_in[9];
  const float* ar1   = (const float*)d_in[10]; const float* b_gat1= (const float*)d_in[11];
  const float* W_gc2 = (const float*)d_in[12]; const float* b_gc2 = (const float*)d_in[13];
  const float* W_gat2= (const float*)d_in[14]; const float* al2   = (const float*)d_in[15];
  const float* ar2   = (const float*)d_in[16]; const float* b_gat2= (const float*)d_in[17];
  const float* W_gc3 = (const float*)d_in[18]; const float* b_gc3 = (const float*)d_in[19];
  const float* W_gat3= (const float*)d_in[20]; const float* al3   = (const float*)d_in[21];
  const float* ar3   = (const float*)d_in[22]; const float* b_gat3= (const float*)d_in[23];
  const float* g1 = (const float*)d_in[24]; const float* be1 = (const float*)d_in[25];
  const float* g2 = (const float*)d_in[26]; const float* be2 = (const float*)d_in[27];
  const float* g3 = (const float*)d_in[28]; const float* be3 = (const float*)d_in[29];

  const size_t NC = (size_t)NN*CC;
  float* A1 = (float*)d_ws;
  float* A2 = A1 + NC;
  float* B  = A2 + NC;
  float* el = B  + NC;            // N*4
  float* er = el + (size_t)NN*4;  // N*4
  float* cs = er + (size_t)NN*4;  // 128
  float* cq = cs + CC;            // 128
  float* bnsc = cq + CC;          // 128
  float* bnsh = bnsc + CC;        // 128
  unsigned short* Wth1 = (unsigned short*)(bnsh + CC);   // 256*512
  unsigned short* Wtl1 = Wth1 + 256*FDIM;
  unsigned short* Wth2 = Wtl1 + 256*FDIM;                // 256*128
  unsigned short* Wtl2 = Wth2 + 256*CC;
  unsigned short* Wth3 = Wtl2 + 256*CC;
  unsigned short* Wtl3 = Wth3 + 256*CC;
  int* offs_i = (int*)(Wtl3 + 256*CC);  // N+1
  int* offs_c = offs_i + (NN+1);  // N+1
  int* deg_i  = offs_c + (NN+1);  // N   (deg_i..dout contiguous: 5N, one memset)
  int* deg_c  = deg_i + NN;       // N
  int* cnt_i  = deg_c + NN;       // N
  int* cnt_c  = cnt_i + NN;       // N
  int* dout   = cnt_c + NN;       // N
  int* eid_i  = dout + NN;        // EI
  int* eid_c  = eid_i + EIE;      // EC

  float* frag = (float*)d_out;        // [G,128]
  float* att  = frag + (size_t)GG*CC; // [N]

  // ---- build CSR + pack weights (per call; inputs re-poisoned each launch) ----
  hipMemsetAsync(deg_i, 0, 5*(size_t)NN*sizeof(int), stream);
  hipMemsetAsync(att, 0, (size_t)NN*sizeof(float), stream);
  k_count<<<cdiv(EIE,256), 256, 0, stream>>>(isrc, idst, cdst, deg_i, deg_c, dout);
  k_scan2<<<2, 256, 0, stream>>>(deg_i, offs_i, deg_c, offs_c);
  k_fill<<<cdiv(EIE,256), 256, 0, stream>>>(isrc, idst, offs_i, cnt_i, eid_i, EIE);
  k_fill<<<cdiv(ECE,256), 256, 0, stream>>>(csrc, cdst, offs_c, cnt_c, eid_c, ECE);
  k_pack_all<<<cdiv(196608,256), 256, 0, stream>>>(W_gc1, W_gat1, W_gc2, W_gat2, W_gc3, W_gat3,
                                                   Wth1, Wtl1, Wth2, Wtl2, Wth3, Wtl3);

  // ---- layers (BN applied as affine inside next consumer) ----
  run_layer<FDIM,4,false,false,true>(feat, b_gc1, al1, ar1, b_gat1, g1, be1,
                                     offs_i, eid_i, offs_c, eid_c, dout, Wth1, Wtl1,
                                     A1, A2, B, el, er, cs, cq, bnsc, bnsh, nullptr, stream);
  run_layer<CC,4,true,false,true>(B, b_gc2, al2, ar2, b_gat2, g2, be2,
                                  offs_i, eid_i, offs_c, eid_c, dout, Wth2, Wtl2,
                                  A1, A2, B, el, er, cs, cq, bnsc, bnsh, nullptr, stream);
  run_layer<CC,1,true,true,false>(B, b_gc3, al3, ar3, b_gat3, g3, be3,
                                  offs_i, eid_i, offs_c, eid_c, dout, Wth3, Wtl3,
                                  A1, A2, B, el, er, cs, cq, bnsc, bnsh, att, stream);

  // ---- pooling with fused layer-3 BN ----
  k_pool_bn<<<GG, 128, 0, stream>>>(B, att, gids, bnsc, bnsh, frag);
}

// Round 6
// 1596.918 us; speedup vs baseline: 1.3254x; 1.3254x over previous
//
#include <hip/hip_runtime.h>
#include <math.h>

#define NN 100000
#define EIE 1600000
#define ECE 800000
#define GG 2000
#define FDIM 512
#define CC 128
#define BNEPS 1e-5f

static inline int cdiv(long a, long b){ return (int)((a+b-1)/b); }

typedef __attribute__((ext_vector_type(8))) short short8;
typedef __attribute__((ext_vector_type(4))) float f32x4;

__device__ __forceinline__ unsigned short f2bf(float f){
  unsigned u = __float_as_uint(f);
  u += 0x7fffu + ((u >> 16) & 1u);
  return (unsigned short)(u >> 16);
}
__device__ __forceinline__ float bf2f(unsigned short h){
  return __uint_as_float(((unsigned)h) << 16);
}
__device__ __forceinline__ float2 ldbf2(const unsigned short* p){
  ushort2 u = *(const ushort2*)p;
  return make_float2(bf2f(u.x), bf2f(u.y));
}

// ---------------- degree counts ----------------
__global__ void k_count(const int* __restrict__ isrc, const int* __restrict__ idst,
                        const int* __restrict__ cdst,
                        int* __restrict__ deg_i, int* __restrict__ deg_c, int* __restrict__ dout) {
  int e = blockIdx.x*256 + threadIdx.x;
  if (e < EIE) { atomicAdd(&deg_i[idst[e]], 1); atomicAdd(&dout[isrc[e]], 1); }
  if (e < ECE) { atomicAdd(&deg_c[cdst[e]], 1); }
}

// ---------------- exclusive scan of the two degree arrays ----------------
__global__ void k_scan2(const int* __restrict__ deg_i, int* __restrict__ offs_i,
                        const int* __restrict__ deg_c, int* __restrict__ offs_c) {
  const int* deg = blockIdx.x ? deg_c : deg_i;
  int* offs      = blockIdx.x ? offs_c : offs_i;
  __shared__ int sums[256];
  int t = threadIdx.x;
  const int chunk = (NN + 255) / 256;
  int lo = t*chunk, hi = min(lo + chunk, NN);
  int s = 0;
  for (int i = lo; i < hi; ++i) s += deg[i];
  sums[t] = s;
  __syncthreads();
  if (t == 0) { int run = 0; for (int i = 0; i < 256; ++i) { int v = sums[i]; sums[i] = run; run += v; } }
  __syncthreads();
  int run = sums[t];
  for (int i = lo; i < hi; ++i) { offs[i] = run; run += deg[i]; }
  if (t == 255) offs[NN] = run;
}

// ---------------- CSR fill ----------------
__global__ void k_fill(const int* __restrict__ src, const int* __restrict__ dst,
                       const int* __restrict__ offs, int* __restrict__ cnt,
                       int* __restrict__ eid, int E) {
  int e = blockIdx.x*256 + threadIdx.x;
  if (e >= E) return;
  int d = dst[e];
  int p = offs[d] + atomicAdd(&cnt[d], 1);
  eid[p] = src[e];
}

// ---------------- pack all W into bf16 hi/lo, k-tile fragment order ----------------
__device__ __forceinline__ size_t wt_off(int n, int k) {
  return (size_t)(k >> 5)*8192 + (((n >> 4)*4 + ((k >> 3) & 3))*16 + (n & 15))*8 + (k & 7);
}
__global__ void k_pack_all(const float* __restrict__ Wgc1, const float* __restrict__ Wgat1,
                           const float* __restrict__ Wgc2, const float* __restrict__ Wgat2,
                           const float* __restrict__ Wgc3, const float* __restrict__ Wgat3,
                           unsigned short* __restrict__ Wth1, unsigned short* __restrict__ Wtl1,
                           unsigned short* __restrict__ Wth2, unsigned short* __restrict__ Wtl2,
                           unsigned short* __restrict__ Wth3, unsigned short* __restrict__ Wtl3) {
  int t = blockIdx.x*256 + threadIdx.x;
  const float *W1, *W2; unsigned short *oh, *ol; int FIN, tt;
  if (t < 131072)      { W1=Wgc1; W2=Wgat1; oh=Wth1; ol=Wtl1; FIN=512; tt=t; }
  else if (t < 163840) { W1=Wgc2; W2=Wgat2; oh=Wth2; ol=Wtl2; FIN=128; tt=t-131072; }
  else if (t < 196608) { W1=Wgc3; W2=Wgat3; oh=Wth3; ol=Wtl3; FIN=128; tt=t-163840; }
  else return;
  int n = tt / FIN, k = tt % FIN;
  float v = (n < 128) ? W1[(size_t)k*128 + n] : W2[(size_t)k*128 + (n-128)];
  unsigned short h = f2bf(v);
  size_t o = wt_off(n, k);
  oh[o] = h;
  ol[o] = f2bf(v - bf2f(h));
}

// ---------------- dual MFMA GEMM (bf16x3): Y1=(x@W1)*dout^-1/2, Y2=x@W2 (bf16 out) ------
template<int FIN, bool BN>
__global__ __launch_bounds__(512)
void k_gemm2(const float* __restrict__ x, const unsigned short* __restrict__ Bh,
             const unsigned short* __restrict__ Bl, const int* __restrict__ rowdeg,
             const float* __restrict__ bnsc, const float* __restrict__ bnsh,
             unsigned short* __restrict__ Y1, unsigned short* __restrict__ Y2) {
  __shared__ __attribute__((aligned(16))) unsigned short sAh[4096];
  __shared__ __attribute__((aligned(16))) unsigned short sAl[4096];
  __shared__ __attribute__((aligned(16))) unsigned short sBh[8192];
  __shared__ __attribute__((aligned(16))) unsigned short sBl[8192];
  int tid = threadIdx.x;
  int row0 = blockIdx.x*128;
  int lane = tid & 63, wid = tid >> 6;
  int wm = wid >> 2, wn = wid & 3;          // 2 x 4 wave grid
  int l15 = lane & 15, quad = lane >> 4;

  f32x4 acc[4][4];
  #pragma unroll
  for (int mt = 0; mt < 4; ++mt)
    #pragma unroll
    for (int nt = 0; nt < 4; ++nt) acc[mt][nt] = (f32x4){0.f,0.f,0.f,0.f};

  for (int k0 = 0; k0 < FIN; k0 += 32) {
    #pragma unroll
    for (int i = 0; i < 2; ++i) {
      int idx = tid + i*512;
      int r = idx >> 3, c = idx & 7;
      int gr = row0 + r; if (gr > NN-1) gr = NN-1;
      float4 v = *(const float4*)(x + (size_t)gr*FIN + k0 + c*4);
      if (BN) {
        float4 s4 = *(const float4*)(bnsc + k0 + c*4);
        float4 h4 = *(const float4*)(bnsh + k0 + c*4);
        v.x = v.x*s4.x + h4.x; v.y = v.y*s4.y + h4.y;
        v.z = v.z*s4.z + h4.z; v.w = v.w*s4.w + h4.w;
      }
      ushort4 hh, ll;
      hh.x = f2bf(v.x); hh.y = f2bf(v.y); hh.z = f2bf(v.z); hh.w = f2bf(v.w);
      ll.x = f2bf(v.x - bf2f(hh.x)); ll.y = f2bf(v.y - bf2f(hh.y));
      ll.z = f2bf(v.z - bf2f(hh.z)); ll.w = f2bf(v.w - bf2f(hh.w));
      int off = (((r>>4)*4 + (c>>1))*16 + (r&15))*8 + (c&1)*4;
      *(ushort4*)&sAh[off] = hh;
      *(ushort4*)&sAl[off] = ll;
    }
    const unsigned short* bhk = Bh + (size_t)k0*256;
    const unsigned short* blk = Bl + (size_t)k0*256;
    #pragma unroll
    for (int i = 0; i < 2; ++i) {
      int idx = tid + i*512;
      *(float4*)&sBh[idx*8] = *(const float4*)(bhk + idx*8);
      *(float4*)&sBl[idx*8] = *(const float4*)(blk + idx*8);
    }
    __syncthreads();
    short8 ah[4], al_[4];
    #pragma unroll
    for (int mt = 0; mt < 4; ++mt) {
      int off = (((wm*4+mt)*4 + quad)*16 + l15)*8;
      ah[mt]  = *(const short8*)&sAh[off];
      al_[mt] = *(const short8*)&sAl[off];
    }
    #pragma unroll
    for (int nt = 0; nt < 4; ++nt) {
      int off = (((wn*4+nt)*4 + quad)*16 + l15)*8;
      short8 bh = *(const short8*)&sBh[off];
      short8 bl = *(const short8*)&sBl[off];
      #pragma unroll
      for (int mt = 0; mt < 4; ++mt) {
        acc[mt][nt] = __builtin_amdgcn_mfma_f32_16x16x32_bf16(ah[mt],  bh, acc[mt][nt], 0,0,0);
        acc[mt][nt] = __builtin_amdgcn_mfma_f32_16x16x32_bf16(ah[mt],  bl, acc[mt][nt], 0,0,0);
        acc[mt][nt] = __builtin_amdgcn_mfma_f32_16x16x32_bf16(al_[mt], bh, acc[mt][nt], 0,0,0);
      }
    }
    __syncthreads();
  }
  // epilogue: D layout col=lane&15, row=quad*4+reg; store bf16
  unsigned short* Y = (wn < 2) ? Y1 : Y2;
  int colbase = (wn & 1)*64;
  #pragma unroll
  for (int mt = 0; mt < 4; ++mt) {
    #pragma unroll
    for (int r = 0; r < 4; ++r) {
      int row = row0 + (wm*4+mt)*16 + quad*4 + r;
      if (row >= NN) continue;
      float sc = (wn < 2) ? rsqrtf((float)max(rowdeg[row], 1)) : 1.0f;
      #pragma unroll
      for (int nt = 0; nt < 4; ++nt)
        Y[(size_t)row*CC + colbase + nt*16 + l15] = f2bf(acc[mt][nt][r]*sc);
    }
  }
}

// ---------------- el/er: wave per node, bf16 loads + shuffle reduce ----------------
template<int H>
__global__ __launch_bounds__(256)
void k_elr2(const unsigned short* __restrict__ f, const float* __restrict__ al,
            const float* __restrict__ ar, float* __restrict__ el, float* __restrict__ er) {
  int lane = threadIdx.x & 63;
  int n = blockIdx.x*4 + (threadIdx.x >> 6);
  if (n >= NN) return;
  int c2 = lane*2;
  float2 v = ldbf2(f + (size_t)n*CC + c2);
  float2 a = *(const float2*)(al + c2);
  float2 b = *(const float2*)(ar + c2);
  float pa = v.x*a.x + v.y*a.y;
  float pb = v.x*b.x + v.y*b.y;
  const int W = (H == 1) ? 64 : 16;
  #pragma unroll
  for (int m = W>>1; m >= 1; m >>= 1) { pa += __shfl_xor(pa, m); pb += __shfl_xor(pb, m); }
  if ((lane & (W-1)) == 0) {
    int h = lane / W;
    el[(size_t)n*H + h] = pa;
    er[(size_t)n*H + h] = pb;
  }
}

// ---------------- fused gather: GraphConv + GAT + biases + leaky, wave per row ----------
// bf16 feature gathers, 4x edge unroll for MLP. Softmax max-shift omitted (shift-invariant).
template<int H, bool ATT, bool LEAKY>
__global__ __launch_bounds__(256)
void k_gather_fused(const unsigned short* __restrict__ A1, const unsigned short* __restrict__ A2,
                    const int* __restrict__ offs_i, const int* __restrict__ eid_i,
                    const int* __restrict__ offs_c, const int* __restrict__ eid_c,
                    const float* __restrict__ el, const float* __restrict__ er,
                    const float* __restrict__ bgc, const float* __restrict__ bgat,
                    float* __restrict__ out, float* __restrict__ att) {
  int lane = threadIdx.x & 63;
  int row = blockIdx.x*4 + (threadIdx.x >> 6);
  if (row >= NN) return;
  int c2 = lane*2;
  // ---- GraphConv over inter in-edges ----
  int lo = offs_i[row], hi = offs_i[row+1];
  float ax = 0.f, ay = 0.f;
  int j = lo;
  for (; j + 3 < hi; j += 4) {
    int s0 = eid_i[j], s1 = eid_i[j+1], s2 = eid_i[j+2], s3 = eid_i[j+3];
    float2 v0 = ldbf2(A1 + (size_t)s0*CC + c2);
    float2 v1 = ldbf2(A1 + (size_t)s1*CC + c2);
    float2 v2 = ldbf2(A1 + (size_t)s2*CC + c2);
    float2 v3 = ldbf2(A1 + (size_t)s3*CC + c2);
    ax += v0.x + v1.x + v2.x + v3.x;
    ay += v0.y + v1.y + v2.y + v3.y;
  }
  for (; j < hi; ++j) {
    int s = eid_i[j];
    float2 v = ldbf2(A1 + (size_t)s*CC + c2);
    ax += v.x; ay += v.y;
  }
  float sc = rsqrtf((float)max(hi - lo, 1));
  // ---- GAT over cross in-edges ----
  int h = (c2*H) >> 7;
  float erd = er[(size_t)row*H + h];
  int lo2 = offs_c[row], hi2 = offs_c[row+1];
  float denom = 0.f;
  j = lo2;
  for (; j + 3 < hi2; j += 4) {
    int s0 = eid_c[j], s1 = eid_c[j+1], s2 = eid_c[j+2], s3 = eid_c[j+3];
    float v0 = el[s0*H+h] + erd, v1 = el[s1*H+h] + erd;
    float v2 = el[s2*H+h] + erd, v3 = el[s3*H+h] + erd;
    v0 = (v0 >= 0.f) ? v0 : 0.2f*v0; v1 = (v1 >= 0.f) ? v1 : 0.2f*v1;
    v2 = (v2 >= 0.f) ? v2 : 0.2f*v2; v3 = (v3 >= 0.f) ? v3 : 0.2f*v3;
    denom += __expf(v0) + __expf(v1) + __expf(v2) + __expf(v3);
  }
  for (; j < hi2; ++j) {
    float v = el[eid_c[j]*H+h] + erd;
    v = (v >= 0.f) ? v : 0.2f*v;
    denom += __expf(v);
  }
  float inv = (denom > 0.f) ? 1.0f/denom : 0.f;
  float gx = 0.f, gy = 0.f;
  j = lo2;
  for (; j + 3 < hi2; j += 4) {
    int s0 = eid_c[j], s1 = eid_c[j+1], s2 = eid_c[j+2], s3 = eid_c[j+3];
    float v0 = el[s0*H+h] + erd, v1 = el[s1*H+h] + erd;
    float v2 = el[s2*H+h] + erd, v3 = el[s3*H+h] + erd;
    v0 = (v0 >= 0.f) ? v0 : 0.2f*v0; v1 = (v1 >= 0.f) ? v1 : 0.2f*v1;
    v2 = (v2 >= 0.f) ? v2 : 0.2f*v2; v3 = (v3 >= 0.f) ? v3 : 0.2f*v3;
    float a0 = __expf(v0)*inv, a1 = __expf(v1)*inv;
    float a2 = __expf(v2)*inv, a3 = __expf(v3)*inv;
    float2 x0 = ldbf2(A2 + (size_t)s0*CC + c2);
    float2 x1 = ldbf2(A2 + (size_t)s1*CC + c2);
    float2 x2 = ldbf2(A2 + (size_t)s2*CC + c2);
    float2 x3 = ldbf2(A2 + (size_t)s3*CC + c2);
    gx += a0*x0.x + a1*x1.x + a2*x2.x + a3*x3.x;
    gy += a0*x0.y + a1*x1.y + a2*x2.y + a3*x3.y;
    if (ATT) { if (lane == 0) { atomicAdd(&att[s0], a0); atomicAdd(&att[s1], a1);
                                atomicAdd(&att[s2], a2); atomicAdd(&att[s3], a3); } }
  }
  for (; j < hi2; ++j) {
    int s = eid_c[j];
    float v = el[s*H+h] + erd;
    v = (v >= 0.f) ? v : 0.2f*v;
    float alpha = __expf(v)*inv;
    float2 x = ldbf2(A2 + (size_t)s*CC + c2);
    gx += alpha*x.x; gy += alpha*x.y;
    if (ATT) { if (lane == 0) atomicAdd(&att[s], alpha); }
  }
  float2 b1 = *(const float2*)(bgc + c2);
  float2 b2 = *(const float2*)(bgat + c2);
  float ox = ax*sc + b1.x + gx + b2.x;
  float oy = ay*sc + b1.y + gy + b2.y;
  if (LEAKY) {
    ox = (ox >= 0.f) ? ox : 0.2f*ox;
    oy = (oy >= 0.f) ? oy : 0.2f*oy;
  }
  *(float2*)(out + (size_t)row*CC + c2) = make_float2(ox, oy);
}

// ---------------- batchnorm stats ----------------
__global__ void k_bn_stats(const float* __restrict__ t, float* __restrict__ cs, float* __restrict__ cq) {
  __shared__ float ls[256], lq[256];
  int col = threadIdx.x & 127, half = threadIdx.x >> 7;
  float s = 0.f, q = 0.f;
  for (int r = blockIdx.x*2 + half; r < NN; r += gridDim.x*2) {
    float v = t[(size_t)r*CC + col]; s += v; q += v*v;
  }
  ls[threadIdx.x] = s; lq[threadIdx.x] = q;
  __syncthreads();
  if (half == 0) {
    atomicAdd(&cs[col], ls[threadIdx.x] + ls[threadIdx.x+128]);
    atomicAdd(&cq[col], lq[threadIdx.x] + lq[threadIdx.x+128]);
  }
}

// ---------------- BN affine coefficients: h = t*sc + sh ----------------
__global__ void k_bn_coef(const float* __restrict__ cs, const float* __restrict__ cq,
                          const float* __restrict__ g, const float* __restrict__ be,
                          float* __restrict__ sc, float* __restrict__ sh) {
  int c = threadIdx.x;
  float mu = cs[c] * (1.f/NN);
  float var = cq[c] * (1.f/NN) - mu*mu;
  float r = rsqrtf(var + BNEPS);
  float s = g[c]*r;
  sc[c] = s;
  sh[c] = be[c] - s*mu;
}

// ---------------- pooling (sorted graph_ids) with fused BN apply ----------------
__global__ void k_pool_bn(const float* __restrict__ t, const float* __restrict__ att,
                          const int* __restrict__ gids, const float* __restrict__ bnsc,
                          const float* __restrict__ bnsh, float* __restrict__ frag) {
  int g = blockIdx.x;
  __shared__ int se[2];
  if (threadIdx.x < 2) {
    int target = g + threadIdx.x;
    int lo = 0, hi = NN;
    while (lo < hi) { int mid = (lo + hi) >> 1; if (gids[mid] < target) lo = mid + 1; else hi = mid; }
    se[threadIdx.x] = lo;
  }
  __syncthreads();
  int lo = se[0], hi = se[1];
  int col = threadIdx.x;
  float scv = bnsc[col], shv = bnsh[col];
  float acc = 0.f;
  for (int n = lo; n < hi; ++n) acc += (t[(size_t)n*CC + col]*scv + shv) * att[n];
  frag[(size_t)g*CC + col] = acc / (float)max(hi - lo, 1);
}

// ---------------- one full layer ----------------
template<int FIN, int H, bool BN, bool ATT, bool LEAKY>
static void run_layer(const float* x, const float* bgc,
                      const float* al, const float* ar, const float* bgat,
                      const float* g, const float* be,
                      const int* offs_i, const int* eid_i, const int* offs_c, const int* eid_c,
                      const int* dout, const unsigned short* Wth, const unsigned short* Wtl,
                      unsigned short* A1, unsigned short* A2, float* B, float* el, float* er,
                      float* cs, float* cq, float* bnsc, float* bnsh,
                      float* att, hipStream_t stream) {
  k_gemm2<FIN,BN><<<cdiv(NN,128), 512, 0, stream>>>(x, Wth, Wtl, dout, bnsc, bnsh, A1, A2);
  k_elr2<H><<<cdiv(NN,4), 256, 0, stream>>>(A2, al, ar, el, er);
  k_gather_fused<H,ATT,LEAKY><<<cdiv(NN,4), 256, 0, stream>>>(A1, A2, offs_i, eid_i,
                                                              offs_c, eid_c, el, er,
                                                              bgc, bgat, B, att);
  hipMemsetAsync(cs, 0, 2*CC*sizeof(float), stream);   // cs,cq contiguous
  k_bn_stats<<<512, 256, 0, stream>>>(B, cs, cq);
  k_bn_coef<<<1, 128, 0, stream>>>(cs, cq, g, be, bnsc, bnsh);
}

extern "C" void kernel_launch(void* const* d_in, const int* in_sizes, int n_in,
                              void* d_out, int out_size, void* d_ws, size_t ws_size,
                              hipStream_t stream) {
  const float* feat  = (const float*)d_in[0];
  const int* isrc    = (const int*)d_in[1];
  const int* idst    = (const int*)d_in[2];
  const int* csrc    = (const int*)d_in[3];
  const int* cdst    = (const int*)d_in[4];
  const int* gids    = (const int*)d_in[5];
  const float* W_gc1 = (const float*)d_in[6];  const float* b_gc1 = (const float*)d_in[7];
  const float* W_gat1= (const float*)d_in[8];  const float* al1   = (const float*)d_in[9];
  const float* ar1   = (const float*)d_in[10]; const float* b_gat1= (const float*)d_in[11];
  const float* W_gc2 = (const float*)d_in[12]; const float* b_gc2 = (const float*)d_in[13];
  const float* W_gat2= (const float*)d_in[14]; const float* al2   = (const float*)d_in[15];
  const float* ar2   = (const float*)d_in[16]; const float* b_gat2= (const float*)d_in[17];
  const float* W_gc3 = (const float*)d_in[18]; const float* b_gc3 = (const float*)d_in[19];
  const float* W_gat3= (const float*)d_in[20]; const float* al3   = (const float*)d_in[21];
  const float* ar3   = (const float*)d_in[22]; const float* b_gat3= (const float*)d_in[23];
  const float* g1 = (const float*)d_in[24]; const float* be1 = (const float*)d_in[25];
  const float* g2 = (const float*)d_in[26]; const float* be2 = (const float*)d_in[27];
  const float* g3 = (const float*)d_in[28]; const float* be3 = (const float*)d_in[29];

  const size_t NC = (size_t)NN*CC;
  float* B  = (float*)d_ws;
  float* el = B  + NC;            // N*4
  float* er = el + (size_t)NN*4;  // N*4
  float* cs = er + (size_t)NN*4;  // 128
  float* cq = cs + CC;            // 128
  float* bnsc = cq + CC;          // 128
  float* bnsh = bnsc + CC;        // 128
  unsigned short* A1 = (unsigned short*)(bnsh + CC);     // NC bf16
  unsigned short* A2 = A1 + NC;                          // NC bf16
  unsigned short* Wth1 = A2 + NC;                        // 256*512
  unsigned short* Wtl1 = Wth1 + 256*FDIM;
  unsigned short* Wth2 = Wtl1 + 256*FDIM;                // 256*128
  unsigned short* Wtl2 = Wth2 + 256*CC;
  unsigned short* Wth3 = Wtl2 + 256*CC;
  unsigned short* Wtl3 = Wth3 + 256*CC;
  int* offs_i = (int*)(Wtl3 + 256*CC);  // N+1
  int* offs_c = offs_i + (NN+1);  // N+1
  int* deg_i  = offs_c + (NN+1);  // N   (deg_i..dout contiguous: 5N, one memset)
  int* deg_c  = deg_i + NN;       // N
  int* cnt_i  = deg_c + NN;       // N
  int* cnt_c  = cnt_i + NN;       // N
  int* dout   = cnt_c + NN;       // N
  int* eid_i  = dout + NN;        // EI
  int* eid_c  = eid_i + EIE;      // EC

  float* frag = (float*)d_out;        // [G,128]
  float* att  = frag + (size_t)GG*CC; // [N]

  // ---- build CSR + pack weights (per call; inputs re-poisoned each launch) ----
  hipMemsetAsync(deg_i, 0, 5*(size_t)NN*sizeof(int), stream);
  hipMemsetAsync(att, 0, (size_t)NN*sizeof(float), stream);
  k_count<<<cdiv(EIE,256), 256, 0, stream>>>(isrc, idst, cdst, deg_i, deg_c, dout);
  k_scan2<<<2, 256, 0, stream>>>(deg_i, offs_i, deg_c, offs_c);
  k_fill<<<cdiv(EIE,256), 256, 0, stream>>>(isrc, idst, offs_i, cnt_i, eid_i, EIE);
  k_fill<<<cdiv(ECE,256), 256, 0, stream>>>(csrc, cdst, offs_c, cnt_c, eid_c, ECE);
  k_pack_all<<<cdiv(196608,256), 256, 0, stream>>>(W_gc1, W_gat1, W_gc2, W_gat2, W_gc3, W_gat3,
                                                   Wth1, Wtl1, Wth2, Wtl2, Wth3, Wtl3);

  // ---- layers (BN applied as affine inside next consumer) ----
  run_layer<FDIM,4,false,false,true>(feat, b_gc1, al1, ar1, b_gat1, g1, be1,
                                     offs_i, eid_i, offs_c, eid_c, dout, Wth1, Wtl1,
                                     A1, A2, B, el, er, cs, cq, bnsc, bnsh, nullptr, stream);
  run_layer<CC,4,true,false,true>(B, b_gc2, al2, ar2, b_gat2, g2, be2,
                                  offs_i, eid_i, offs_c, eid_c, dout, Wth2, Wtl2,
                                  A1, A2, B, el, er, cs, cq, bnsc, bnsh, nullptr, stream);
  run_layer<CC,1,true,true,false>(B, b_gc3, al3, ar3, b_gat3, g3, be3,
                                  offs_i, eid_i, offs_c, eid_c, dout, Wth3, Wtl3,
                                  A1, A2, B, el, er, cs, cq, bnsc, bnsh, att, stream);

  // ---- pooling with fused layer-3 BN ----
  k_pool_bn<<<GG, 128, 0, stream>>>(B, att, gids, bnsc, bnsh, frag);
}

// Round 7
// 1352.613 us; speedup vs baseline: 1.5648x; 1.1806x over previous
//
#include <hip/hip_runtime.h>
#include <math.h>

#define NN 100000
#define EIE 1600000
#define ECE 800000
#define GG 2000
#define FDIM 512
#define CC 128
#define BNEPS 1e-5f
#define CHUNKS 782   // ceil(2*NN/256)

static inline int cdiv(long a, long b){ return (int)((a+b-1)/b); }

typedef __attribute__((ext_vector_type(8))) short short8;
typedef __attribute__((ext_vector_type(4))) float f32x4;

__device__ __forceinline__ unsigned short f2bf(float f){
  unsigned u = __float_as_uint(f);
  u += 0x7fffu + ((u >> 16) & 1u);
  return (unsigned short)(u >> 16);
}
__device__ __forceinline__ float bf2f(unsigned short h){
  return __uint_as_float(((unsigned)h) << 16);
}
__device__ __forceinline__ float2 ldbf2(const unsigned short* p){
  ushort2 u = *(const ushort2*)p;
  return make_float2(bf2f(u.x), bf2f(u.y));
}

// ---------------- degree counts (+ att zero) ----------------
__global__ void k_count(const int* __restrict__ isrc, const int* __restrict__ idst,
                        const int* __restrict__ cdst,
                        int* __restrict__ deg_i, int* __restrict__ deg_c, int* __restrict__ dout,
                        float* __restrict__ att) {
  int e = blockIdx.x*256 + threadIdx.x;
  if (e < EIE) { atomicAdd(&deg_i[idst[e]], 1); atomicAdd(&dout[isrc[e]], 1); }
  if (e < ECE) { atomicAdd(&deg_c[cdst[e]], 1); }
  if (e < NN)  { att[e] = 0.f; }
}

// ---------------- parallel 3-phase exclusive scan over concat [deg_i; deg_c] ----------
__global__ void k_scan_p1(const int* __restrict__ deg, int* __restrict__ csum) {
  __shared__ int s[256];
  int idx = blockIdx.x*256 + threadIdx.x;
  s[threadIdx.x] = (idx < 2*NN) ? deg[idx] : 0;
  __syncthreads();
  for (int o = 128; o >= 1; o >>= 1) {
    if (threadIdx.x < o) s[threadIdx.x] += s[threadIdx.x + o];
    __syncthreads();
  }
  if (threadIdx.x == 0) csum[blockIdx.x] = s[0];
}
__global__ __launch_bounds__(1024) void k_scan_p2(int* __restrict__ csum) {
  __shared__ int s[1024];
  int t = threadIdx.x;
  s[t] = (t < CHUNKS) ? csum[t] : 0;
  __syncthreads();
  for (int o = 1; o < 1024; o <<= 1) {
    int v = (t >= o) ? s[t-o] : 0;
    __syncthreads();
    s[t] += v;
    __syncthreads();
  }
  if (t < CHUNKS) csum[t] = (t == 0) ? 0 : s[t-1];
}
__global__ void k_scan_p3(const int* __restrict__ deg, const int* __restrict__ csum,
                          int* __restrict__ offs_i, int* __restrict__ offs_c) {
  __shared__ int s[256];
  int t = threadIdx.x;
  int idx = blockIdx.x*256 + t;
  int v = (idx < 2*NN) ? deg[idx] : 0;
  s[t] = v;
  __syncthreads();
  for (int o = 1; o < 256; o <<= 1) {
    int u = (t >= o) ? s[t-o] : 0;
    __syncthreads();
    s[t] += u;
    __syncthreads();
  }
  int excl = csum[blockIdx.x] + s[t] - v;
  if (idx < NN) offs_i[idx] = excl;
  else if (idx < 2*NN) offs_c[idx-NN] = excl - EIE;
  if (idx == 0) { offs_i[NN] = EIE; offs_c[NN] = ECE; }
}

// ---------------- CSR fill (both edge lists) ----------------
__global__ void k_fill2(const int* __restrict__ isrc, const int* __restrict__ idst,
                        const int* __restrict__ csrc, const int* __restrict__ cdst,
                        const int* __restrict__ offs_i, int* __restrict__ cnt_i, int* __restrict__ eid_i,
                        const int* __restrict__ offs_c, int* __restrict__ cnt_c, int* __restrict__ eid_c) {
  int e = blockIdx.x*256 + threadIdx.x;
  if (e < EIE) { int d = idst[e]; int p = offs_i[d] + atomicAdd(&cnt_i[d], 1); eid_i[p] = isrc[e]; }
  if (e < ECE) { int d = cdst[e]; int p = offs_c[d] + atomicAdd(&cnt_c[d], 1); eid_c[p] = csrc[e]; }
}

// ---------------- pack all W into bf16 hi/lo, k-tile fragment order ----------------
__device__ __forceinline__ size_t wt_off(int n, int k) {
  return (size_t)(k >> 5)*8192 + (((n >> 4)*4 + ((k >> 3) & 3))*16 + (n & 15))*8 + (k & 7);
}
__global__ void k_pack_all(const float* __restrict__ Wgc1, const float* __restrict__ Wgat1,
                           const float* __restrict__ Wgc2, const float* __restrict__ Wgat2,
                           const float* __restrict__ Wgc3, const float* __restrict__ Wgat3,
                           unsigned short* __restrict__ Wth1, unsigned short* __restrict__ Wtl1,
                           unsigned short* __restrict__ Wth2, unsigned short* __restrict__ Wtl2,
                           unsigned short* __restrict__ Wth3, unsigned short* __restrict__ Wtl3) {
  int t = blockIdx.x*256 + threadIdx.x;
  const float *W1, *W2; unsigned short *oh, *ol; int FIN, tt;
  if (t < 131072)      { W1=Wgc1; W2=Wgat1; oh=Wth1; ol=Wtl1; FIN=512; tt=t; }
  else if (t < 163840) { W1=Wgc2; W2=Wgat2; oh=Wth2; ol=Wtl2; FIN=128; tt=t-131072; }
  else if (t < 196608) { W1=Wgc3; W2=Wgat3; oh=Wth3; ol=Wtl3; FIN=128; tt=t-163840; }
  else return;
  int n = tt / FIN, k = tt % FIN;
  float v = (n < 128) ? W1[(size_t)k*128 + n] : W2[(size_t)k*128 + (n-128)];
  unsigned short h = f2bf(v);
  size_t o = wt_off(n, k);
  oh[o] = h;
  ol[o] = f2bf(v - bf2f(h));
}

// ---------------- dual MFMA GEMM (bf16x2): Y1=(x@W1)*dout^-1/2, Y2=x@W2 (bf16 out) ------
// x-side bf16 (exact for bf16 inputs), W-side hi+lo. 128x256 tile, 8 waves (2x4).
template<int FIN, bool BF16IN, bool BN>
__global__ __launch_bounds__(512)
void k_gemm2(const float* __restrict__ xf, const unsigned short* __restrict__ xb,
             const unsigned short* __restrict__ Bh, const unsigned short* __restrict__ Bl,
             const int* __restrict__ rowdeg,
             const float* __restrict__ bnsc, const float* __restrict__ bnsh,
             unsigned short* __restrict__ Y1, unsigned short* __restrict__ Y2) {
  __shared__ __attribute__((aligned(16))) unsigned short sAh[4096];   // 8 KB
  __shared__ __attribute__((aligned(16))) unsigned short sBh[8192];   // 16 KB
  __shared__ __attribute__((aligned(16))) unsigned short sBl[8192];   // 16 KB
  int tid = threadIdx.x;
  int row0 = blockIdx.x*128;
  int lane = tid & 63, wid = tid >> 6;
  int wm = wid >> 2, wn = wid & 3;          // 2 x 4 wave grid
  int l15 = lane & 15, quad = lane >> 4;

  f32x4 acc[4][4];
  #pragma unroll
  for (int mt = 0; mt < 4; ++mt)
    #pragma unroll
    for (int nt = 0; nt < 4; ++nt) acc[mt][nt] = (f32x4){0.f,0.f,0.f,0.f};

  for (int k0 = 0; k0 < FIN; k0 += 32) {
    if (BF16IN) {
      // 128 rows x 32 k bf16: 512 threads x 16B
      int r = tid >> 2, c16 = tid & 3;
      int gr = row0 + r; if (gr > NN-1) gr = NN-1;
      short8 u = *(const short8*)(xb + (size_t)gr*CC + k0 + c16*8);
      short8 o;
      #pragma unroll
      for (int j = 0; j < 8; ++j) {
        float f = bf2f((unsigned short)u[j]);
        if (BN) f = f*bnsc[k0 + c16*8 + j] + bnsh[k0 + c16*8 + j];
        o[j] = (short)f2bf(f);
      }
      *(short8*)&sAh[(((r>>4)*4 + c16)*16 + (r&15))*8] = o;
    } else {
      #pragma unroll
      for (int i = 0; i < 2; ++i) {
        int idx = tid + i*512;
        int r = idx >> 3, c = idx & 7;
        int gr = row0 + r; if (gr > NN-1) gr = NN-1;
        float4 v = *(const float4*)(xf + (size_t)gr*FIN + k0 + c*4);
        ushort4 hh;
        hh.x = f2bf(v.x); hh.y = f2bf(v.y); hh.z = f2bf(v.z); hh.w = f2bf(v.w);
        *(ushort4*)&sAh[(((r>>4)*4 + (c>>1))*16 + (r&15))*8 + (c&1)*4] = hh;
      }
    }
    const unsigned short* bhk = Bh + (size_t)k0*256;
    const unsigned short* blk = Bl + (size_t)k0*256;
    #pragma unroll
    for (int i = 0; i < 2; ++i) {
      int idx = tid + i*512;
      *(float4*)&sBh[idx*8] = *(const float4*)(bhk + idx*8);
      *(float4*)&sBl[idx*8] = *(const float4*)(blk + idx*8);
    }
    __syncthreads();
    short8 ah[4];
    #pragma unroll
    for (int mt = 0; mt < 4; ++mt)
      ah[mt] = *(const short8*)&sAh[(((wm*4+mt)*4 + quad)*16 + l15)*8];
    #pragma unroll
    for (int nt = 0; nt < 4; ++nt) {
      int off = (((wn*4+nt)*4 + quad)*16 + l15)*8;
      short8 bh = *(const short8*)&sBh[off];
      short8 bl = *(const short8*)&sBl[off];
      #pragma unroll
      for (int mt = 0; mt < 4; ++mt) {
        acc[mt][nt] = __builtin_amdgcn_mfma_f32_16x16x32_bf16(ah[mt], bh, acc[mt][nt], 0,0,0);
        acc[mt][nt] = __builtin_amdgcn_mfma_f32_16x16x32_bf16(ah[mt], bl, acc[mt][nt], 0,0,0);
      }
    }
    __syncthreads();
  }
  // epilogue: D layout col=lane&15, row=quad*4+reg; bf16 store
  unsigned short* Y = (wn < 2) ? Y1 : Y2;
  int colbase = (wn & 1)*64;
  #pragma unroll
  for (int mt = 0; mt < 4; ++mt) {
    #pragma unroll
    for (int r = 0; r < 4; ++r) {
      int row = row0 + (wm*4+mt)*16 + quad*4 + r;
      if (row >= NN) continue;
      float sc = (wn < 2) ? rsqrtf((float)max(rowdeg[row], 1)) : 1.0f;
      #pragma unroll
      for (int nt = 0; nt < 4; ++nt)
        Y[(size_t)row*CC + colbase + nt*16 + l15] = f2bf(acc[mt][nt][r]*sc);
    }
  }
}

// ---------------- el/er: wave per node, bf16 loads + shuffle reduce (+csq zero) ---------
template<int H>
__global__ __launch_bounds__(256)
void k_elr2(const unsigned short* __restrict__ f, const float* __restrict__ al,
            const float* __restrict__ ar, float* __restrict__ el, float* __restrict__ er,
            float* __restrict__ csq) {
  if (blockIdx.x == 0) csq[threadIdx.x] = 0.f;   // zero cs/cq (256 floats) for bn_stats
  int lane = threadIdx.x & 63;
  int n = blockIdx.x*4 + (threadIdx.x >> 6);
  if (n >= NN) return;
  int c2 = lane*2;
  float2 v = ldbf2(f + (size_t)n*CC + c2);
  float2 a = *(const float2*)(al + c2);
  float2 b = *(const float2*)(ar + c2);
  float pa = v.x*a.x + v.y*a.y;
  float pb = v.x*b.x + v.y*b.y;
  const int W = (H == 1) ? 64 : 16;
  #pragma unroll
  for (int m = W>>1; m >= 1; m >>= 1) { pa += __shfl_xor(pa, m); pb += __shfl_xor(pb, m); }
  if ((lane & (W-1)) == 0) {
    int h = lane / W;
    el[(size_t)n*H + h] = pa;
    er[(size_t)n*H + h] = pb;
  }
}

// ---------------- fused gather: GraphConv + GAT + biases + leaky, wave per row ----------
template<int H, bool ATT, bool LEAKY>
__global__ __launch_bounds__(256)
void k_gather_fused(const unsigned short* __restrict__ A1, const unsigned short* __restrict__ A2,
                    const int* __restrict__ offs_i, const int* __restrict__ eid_i,
                    const int* __restrict__ offs_c, const int* __restrict__ eid_c,
                    const float* __restrict__ el, const float* __restrict__ er,
                    const float* __restrict__ bgc, const float* __restrict__ bgat,
                    unsigned short* __restrict__ out, float* __restrict__ att) {
  int lane = threadIdx.x & 63;
  int row = blockIdx.x*4 + (threadIdx.x >> 6);
  if (row >= NN) return;
  int c2 = lane*2;
  // ---- GraphConv over inter in-edges ----
  int lo = offs_i[row], hi = offs_i[row+1];
  float ax = 0.f, ay = 0.f;
  int j = lo;
  for (; j + 3 < hi; j += 4) {
    int s0 = eid_i[j], s1 = eid_i[j+1], s2 = eid_i[j+2], s3 = eid_i[j+3];
    float2 v0 = ldbf2(A1 + (size_t)s0*CC + c2);
    float2 v1 = ldbf2(A1 + (size_t)s1*CC + c2);
    float2 v2 = ldbf2(A1 + (size_t)s2*CC + c2);
    float2 v3 = ldbf2(A1 + (size_t)s3*CC + c2);
    ax += v0.x + v1.x + v2.x + v3.x;
    ay += v0.y + v1.y + v2.y + v3.y;
  }
  for (; j < hi; ++j) {
    int s = eid_i[j];
    float2 v = ldbf2(A1 + (size_t)s*CC + c2);
    ax += v.x; ay += v.y;
  }
  float sc = rsqrtf((float)max(hi - lo, 1));
  // ---- GAT over cross in-edges (max-shift omitted: shift-invariant) ----
  int h = (c2*H) >> 7;
  float erd = er[(size_t)row*H + h];
  int lo2 = offs_c[row], hi2 = offs_c[row+1];
  float denom = 0.f;
  j = lo2;
  for (; j + 3 < hi2; j += 4) {
    int s0 = eid_c[j], s1 = eid_c[j+1], s2 = eid_c[j+2], s3 = eid_c[j+3];
    float v0 = el[s0*H+h] + erd, v1 = el[s1*H+h] + erd;
    float v2 = el[s2*H+h] + erd, v3 = el[s3*H+h] + erd;
    v0 = (v0 >= 0.f) ? v0 : 0.2f*v0; v1 = (v1 >= 0.f) ? v1 : 0.2f*v1;
    v2 = (v2 >= 0.f) ? v2 : 0.2f*v2; v3 = (v3 >= 0.f) ? v3 : 0.2f*v3;
    denom += __expf(v0) + __expf(v1) + __expf(v2) + __expf(v3);
  }
  for (; j < hi2; ++j) {
    float v = el[eid_c[j]*H+h] + erd;
    v = (v >= 0.f) ? v : 0.2f*v;
    denom += __expf(v);
  }
  float inv = (denom > 0.f) ? 1.0f/denom : 0.f;
  float gx = 0.f, gy = 0.f;
  j = lo2;
  for (; j + 3 < hi2; j += 4) {
    int s0 = eid_c[j], s1 = eid_c[j+1], s2 = eid_c[j+2], s3 = eid_c[j+3];
    float v0 = el[s0*H+h] + erd, v1 = el[s1*H+h] + erd;
    float v2 = el[s2*H+h] + erd, v3 = el[s3*H+h] + erd;
    v0 = (v0 >= 0.f) ? v0 : 0.2f*v0; v1 = (v1 >= 0.f) ? v1 : 0.2f*v1;
    v2 = (v2 >= 0.f) ? v2 : 0.2f*v2; v3 = (v3 >= 0.f) ? v3 : 0.2f*v3;
    float a0 = __expf(v0)*inv, a1 = __expf(v1)*inv;
    float a2 = __expf(v2)*inv, a3 = __expf(v3)*inv;
    float2 x0 = ldbf2(A2 + (size_t)s0*CC + c2);
    float2 x1 = ldbf2(A2 + (size_t)s1*CC + c2);
    float2 x2 = ldbf2(A2 + (size_t)s2*CC + c2);
    float2 x3 = ldbf2(A2 + (size_t)s3*CC + c2);
    gx += a0*x0.x + a1*x1.x + a2*x2.x + a3*x3.x;
    gy += a0*x0.y + a1*x1.y + a2*x2.y + a3*x3.y;
    if (ATT) { if (lane == 0) { atomicAdd(&att[s0], a0); atomicAdd(&att[s1], a1);
                                atomicAdd(&att[s2], a2); atomicAdd(&att[s3], a3); } }
  }
  for (; j < hi2; ++j) {
    int s = eid_c[j];
    float v = el[s*H+h] + erd;
    v = (v >= 0.f) ? v : 0.2f*v;
    float alpha = __expf(v)*inv;
    float2 x = ldbf2(A2 + (size_t)s*CC + c2);
    gx += alpha*x.x; gy += alpha*x.y;
    if (ATT) { if (lane == 0) atomicAdd(&att[s], alpha); }
  }
  float2 b1 = *(const float2*)(bgc + c2);
  float2 b2 = *(const float2*)(bgat + c2);
  float ox = ax*sc + b1.x + gx + b2.x;
  float oy = ay*sc + b1.y + gy + b2.y;
  if (LEAKY) {
    ox = (ox >= 0.f) ? ox : 0.2f*ox;
    oy = (oy >= 0.f) ? oy : 0.2f*oy;
  }
  ushort2 ov; ov.x = f2bf(ox); ov.y = f2bf(oy);
  *(ushort2*)(out + (size_t)row*CC + c2) = ov;
}

// ---------------- batchnorm stats (bf16 input): csq[0:128]=sum, [128:256]=sumsq --------
__global__ __launch_bounds__(256)
void k_bn_stats(const unsigned short* __restrict__ t, float* __restrict__ csq) {
  __shared__ float red[4][128];
  int lane = threadIdx.x & 63, g = threadIdx.x >> 6;
  int c2 = lane*2;
  float s0=0.f, s1=0.f, q0=0.f, q1=0.f;
  for (int r = blockIdx.x*4 + g; r < NN; r += gridDim.x*4) {
    float2 v = ldbf2(t + (size_t)r*CC + c2);
    s0 += v.x; s1 += v.y; q0 += v.x*v.x; q1 += v.y*v.y;
  }
  red[g][c2] = s0; red[g][c2+1] = s1;
  __syncthreads();
  if (threadIdx.x < 128) {
    float a = red[0][threadIdx.x] + red[1][threadIdx.x] + red[2][threadIdx.x] + red[3][threadIdx.x];
    atomicAdd(&csq[threadIdx.x], a);
  }
  __syncthreads();
  red[g][c2] = q0; red[g][c2+1] = q1;
  __syncthreads();
  if (threadIdx.x < 128) {
    float a = red[0][threadIdx.x] + red[1][threadIdx.x] + red[2][threadIdx.x] + red[3][threadIdx.x];
    atomicAdd(&csq[128 + threadIdx.x], a);
  }
}

// ---------------- BN affine coefficients: h = t*sc + sh ----------------
__global__ void k_bn_coef(const float* __restrict__ csq,
                          const float* __restrict__ g, const float* __restrict__ be,
                          float* __restrict__ sc, float* __restrict__ sh) {
  int c = threadIdx.x;
  float mu = csq[c] * (1.f/NN);
  float var = csq[128+c] * (1.f/NN) - mu*mu;
  float r = rsqrtf(var + BNEPS);
  float s = g[c]*r;
  sc[c] = s;
  sh[c] = be[c] - s*mu;
}

// ---------------- pooling (sorted graph_ids) with fused BN apply ----------------
__global__ void k_pool_bn(const unsigned short* __restrict__ t, const float* __restrict__ att,
                          const int* __restrict__ gids, const float* __restrict__ bnsc,
                          const float* __restrict__ bnsh, float* __restrict__ frag) {
  int g = blockIdx.x;
  __shared__ int se[2];
  if (threadIdx.x < 2) {
    int target = g + threadIdx.x;
    int lo = 0, hi = NN;
    while (lo < hi) { int mid = (lo + hi) >> 1; if (gids[mid] < target) lo = mid + 1; else hi = mid; }
    se[threadIdx.x] = lo;
  }
  __syncthreads();
  int lo = se[0], hi = se[1];
  int col = threadIdx.x;
  float scv = bnsc[col], shv = bnsh[col];
  float acc = 0.f;
  for (int n = lo; n < hi; ++n) acc += (bf2f(t[(size_t)n*CC + col])*scv + shv) * att[n];
  frag[(size_t)g*CC + col] = acc / (float)max(hi - lo, 1);
}

// ---------------- one full layer ----------------
template<int FIN, int H, bool BF16IN, bool BN, bool ATT, bool LEAKY>
static void run_layer(const float* xf, const unsigned short* xb, const float* bgc,
                      const float* al, const float* ar, const float* bgat,
                      const float* g, const float* be,
                      const int* offs_i, const int* eid_i, const int* offs_c, const int* eid_c,
                      const int* dout, const unsigned short* Wth, const unsigned short* Wtl,
                      unsigned short* A1, unsigned short* A2, unsigned short* B,
                      float* el, float* er, float* csq, float* bnsc, float* bnsh,
                      float* att, hipStream_t stream) {
  k_gemm2<FIN,BF16IN,BN><<<cdiv(NN,128), 512, 0, stream>>>(xf, xb, Wth, Wtl, dout, bnsc, bnsh, A1, A2);
  k_elr2<H><<<cdiv(NN,4), 256, 0, stream>>>(A2, al, ar, el, er, csq);
  k_gather_fused<H,ATT,LEAKY><<<cdiv(NN,4), 256, 0, stream>>>(A1, A2, offs_i, eid_i,
                                                              offs_c, eid_c, el, er,
                                                              bgc, bgat, B, att);
  k_bn_stats<<<256, 256, 0, stream>>>(B, csq);
  k_bn_coef<<<1, 128, 0, stream>>>(csq, g, be, bnsc, bnsh);
}

extern "C" void kernel_launch(void* const* d_in, const int* in_sizes, int n_in,
                              void* d_out, int out_size, void* d_ws, size_t ws_size,
                              hipStream_t stream) {
  const float* feat  = (const float*)d_in[0];
  const int* isrc    = (const int*)d_in[1];
  const int* idst    = (const int*)d_in[2];
  const int* csrc    = (const int*)d_in[3];
  const int* cdst    = (const int*)d_in[4];
  const int* gids    = (const int*)d_in[5];
  const float* W_gc1 = (const float*)d_in[6];  const float* b_gc1 = (const float*)d_in[7];
  const float* W_gat1= (const float*)d_in[8];  const float* al1   = (const float*)d_in[9];
  const float* ar1   = (const float*)d_in[10]; const float* b_gat1= (const float*)d_in[11];
  const float* W_gc2 = (const float*)d_in[12]; const float* b_gc2 = (const float*)d_in[13];
  const float* W_gat2= (const float*)d_in[14]; const float* al2   = (const float*)d_in[15];
  const float* ar2   = (const float*)d_in[16]; const float* b_gat2= (const float*)d_in[17];
  const float* W_gc3 = (const float*)d_in[18]; const float* b_gc3 = (const float*)d_in[19];
  const float* W_gat3= (const float*)d_in[20]; const float* al3   = (const float*)d_in[21];
  const float* ar3   = (const float*)d_in[22]; const float* b_gat3= (const float*)d_in[23];
  const float* g1 = (const float*)d_in[24]; const float* be1 = (const float*)d_in[25];
  const float* g2 = (const float*)d_in[26]; const float* be2 = (const float*)d_in[27];
  const float* g3 = (const float*)d_in[28]; const float* be3 = (const float*)d_in[29];

  const size_t NC = (size_t)NN*CC;
  float* el   = (float*)d_ws;           // N*4
  float* er   = el + (size_t)NN*4;      // N*4
  float* csq  = er + (size_t)NN*4;      // 256 (sum | sumsq)
  float* bnsc = csq + 256;              // 128
  float* bnsh = bnsc + CC;              // 128
  unsigned short* B  = (unsigned short*)(bnsh + CC);     // NC bf16
  unsigned short* A1 = B + NC;                           // NC bf16
  unsigned short* A2 = A1 + NC;                          // NC bf16
  unsigned short* Wth1 = A2 + NC;                        // 256*512
  unsigned short* Wtl1 = Wth1 + 256*FDIM;
  unsigned short* Wth2 = Wtl1 + 256*FDIM;                // 256*128
  unsigned short* Wtl2 = Wth2 + 256*CC;
  unsigned short* Wth3 = Wtl2 + 256*CC;
  unsigned short* Wtl3 = Wth3 + 256*CC;
  int* csum   = (int*)(Wtl3 + 256*CC);  // 1024
  int* offs_i = csum + 1024;            // N+1
  int* offs_c = offs_i + (NN+1);        // N+1
  int* deg_i  = offs_c + (NN+1);        // N  (deg_i,deg_c contiguous for concat scan;
  int* deg_c  = deg_i + NN;             // N   deg_i..dout contiguous: 5N, one memset)
  int* cnt_i  = deg_c + NN;             // N
  int* cnt_c  = cnt_i + NN;             // N
  int* dout   = cnt_c + NN;             // N
  int* eid_i  = dout + NN;              // EI
  int* eid_c  = eid_i + EIE;            // EC

  float* frag = (float*)d_out;          // [G,128]
  float* att  = frag + (size_t)GG*CC;   // [N]

  // ---- build CSR + pack weights (per call) ----
  hipMemsetAsync(deg_i, 0, 5*(size_t)NN*sizeof(int), stream);
  k_count<<<cdiv(EIE,256), 256, 0, stream>>>(isrc, idst, cdst, deg_i, deg_c, dout, att);
  k_scan_p1<<<CHUNKS, 256, 0, stream>>>(deg_i, csum);
  k_scan_p2<<<1, 1024, 0, stream>>>(csum);
  k_scan_p3<<<CHUNKS, 256, 0, stream>>>(deg_i, csum, offs_i, offs_c);
  k_fill2<<<cdiv(EIE,256), 256, 0, stream>>>(isrc, idst, csrc, cdst,
                                             offs_i, cnt_i, eid_i, offs_c, cnt_c, eid_c);
  k_pack_all<<<cdiv(196608,256), 256, 0, stream>>>(W_gc1, W_gat1, W_gc2, W_gat2, W_gc3, W_gat3,
                                                   Wth1, Wtl1, Wth2, Wtl2, Wth3, Wtl3);

  // ---- layers (BN applied as affine inside next consumer) ----
  run_layer<FDIM,4,false,false,false,true>(feat, nullptr, b_gc1, al1, ar1, b_gat1, g1, be1,
                                           offs_i, eid_i, offs_c, eid_c, dout, Wth1, Wtl1,
                                           A1, A2, B, el, er, csq, bnsc, bnsh, nullptr, stream);
  run_layer<CC,4,true,true,false,true>(nullptr, B, b_gc2, al2, ar2, b_gat2, g2, be2,
                                       offs_i, eid_i, offs_c, eid_c, dout, Wth2, Wtl2,
                                       A1, A2, B, el, er, csq, bnsc, bnsh, nullptr, stream);
  run_layer<CC,1,true,true,true,false>(nullptr, B, b_gc3, al3, ar3, b_gat3, g3, be3,
                                       offs_i, eid_i, offs_c, eid_c, dout, Wth3, Wtl3,
                                       A1, A2, B, el, er, csq, bnsc, bnsh, att, stream);

  // ---- pooling with fused layer-3 BN ----
  k_pool_bn<<<GG, 128, 0, stream>>>(B, att, gids, bnsc, bnsh, frag);
}